// Round 1
// baseline (162.581 us; speedup 1.0000x reference)
//
#include <hip/hip_runtime.h>

#define CROPPX 4
#define H 504
#define W 504
#define IMG 512
#define NB 16
#define NCH 3
#define KS 11
#define RAD 5
#define TW 64               // output cols per block
#define STRIP (TW + 2*RAD)  // 74 input cols per block
#define RPS 42              // output rows per segment
#define NSEG 12             // 12 * 42 = 504
#define NXT 8               // ceil(504/64): last tile has 56 valid cols

__global__ __launch_bounds__(64) void ssim_main(const float* __restrict__ img1,
                                                const float* __restrict__ img2,
                                                double* __restrict__ partial) {
    const int tid = threadIdx.x;
    const int gx0 = blockIdx.x * TW;   // first output col of tile
    const int y0  = blockIdx.y * RPS;  // first output row of segment
    const int b   = blockIdx.z;        // batch
    const int nrows = (y0 + RPS <= H) ? RPS : (H - y0);

    __shared__ float rowA[STRIP];
    __shared__ float rowB[STRIP];
    __shared__ float hist[KS][5][TW];  // h-sum history ring (11 rows x 5 stats)

    // zero the history ring
    for (int i = tid; i < KS * 5 * TW; i += 64) ((float*)hist)[i] = 0.f;

    const float* p1 = img1 + (size_t)(b * NCH) * IMG * IMG;  // channel 0
    const float* p2 = img2 + (size_t)(b * NCH) * IMG * IMG;

    double vs1 = 0, vs2 = 0, vs11 = 0, vs22 = 0, vs12 = 0;
    double ssum = 0.0;
    const double C1 = 6.5025, C2 = 58.5225;
    const double inv121 = 1.0 / 121.0;
    const bool colValid = (gx0 + tid) < W;

    for (int iter = 0; iter < nrows + 2 * RAD; ++iter) {
        const int r = y0 - RAD + iter;  // cropped input row being ingested
        __syncthreads();                // protect rowA/rowB reuse
        const bool rowIn = (r >= 0) && (r < H);
        for (int s = tid; s < STRIP; s += 64) {
            const int c = gx0 - RAD + s;  // cropped col
            float a = 0.f, bb = 0.f;
            if (rowIn && c >= 0 && c < W) {
                const size_t off = (size_t)(r + CROPPX) * IMG + (c + CROPPX);
                a  = p1[off];
                bb = p2[off];
            }
            rowA[s] = a;
            rowB[s] = bb;
        }
        __syncthreads();

        // horizontal 11-tap sums for output column (gx0 + tid)
        float h1 = 0, h2 = 0, h11 = 0, h22 = 0, h12 = 0;
        #pragma unroll
        for (int dx = 0; dx < KS; ++dx) {
            const float a = rowA[tid + dx];
            const float c = rowB[tid + dx];
            h1 += a;
            h2 += c;
            h11 = fmaf(a, a, h11);
            h22 = fmaf(c, c, h22);
            h12 = fmaf(a, c, h12);
        }

        // vertical sliding window: add new row, subtract row from 11 iters ago
        const int ring = iter % KS;  // wave-uniform
        vs1  += (double)h1  - (double)hist[ring][0][tid];
        vs2  += (double)h2  - (double)hist[ring][1][tid];
        vs11 += (double)h11 - (double)hist[ring][2][tid];
        vs22 += (double)h22 - (double)hist[ring][3][tid];
        vs12 += (double)h12 - (double)hist[ring][4][tid];
        hist[ring][0][tid] = h1;
        hist[ring][1][tid] = h2;
        hist[ring][2][tid] = h11;
        hist[ring][3][tid] = h22;
        hist[ring][4][tid] = h12;

        // after ingesting row r, vs covers rows [r-10, r] = window of output row r-5
        if (iter >= 2 * RAD && colValid) {
            const double mu1 = vs1 * inv121;
            const double mu2 = vs2 * inv121;
            const double mu1s = mu1 * mu1;
            const double mu2s = mu2 * mu2;
            const double m12  = mu1 * mu2;
            const double s1  = vs11 * inv121 - mu1s;
            const double s2  = vs22 * inv121 - mu2s;
            const double s12 = vs12 * inv121 - m12;
            const double num = (2.0 * m12 + C1) * (2.0 * s12 + C2);
            const double den = (mu1s + mu2s + C1) * (s1 + s2 + C2);
            ssum += num / den;
        }
    }

    // wave (64-lane) reduction of ssum
    for (int off = 32; off > 0; off >>= 1)
        ssum += __shfl_down(ssum, off);
    if (tid == 0) {
        const int bidx = (blockIdx.z * gridDim.y + blockIdx.y) * gridDim.x + blockIdx.x;
        partial[bidx] = ssum;
    }
}

__global__ __launch_bounds__(256) void ssim_final(const double* __restrict__ partial,
                                                  int n, float* __restrict__ out) {
    __shared__ double sh[256];
    double s = 0.0;
    for (int i = threadIdx.x; i < n; i += 256) s += partial[i];
    sh[threadIdx.x] = s;
    __syncthreads();
    for (int stride = 128; stride > 0; stride >>= 1) {
        if (threadIdx.x < stride) sh[threadIdx.x] += sh[threadIdx.x + stride];
        __syncthreads();
    }
    if (threadIdx.x == 0)
        out[0] = (float)(sh[0] / ((double)NB * (double)H * (double)W));
}

extern "C" void kernel_launch(void* const* d_in, const int* in_sizes, int n_in,
                              void* d_out, int out_size, void* d_ws, size_t ws_size,
                              hipStream_t stream) {
    const float* img1 = (const float*)d_in[0];
    const float* img2 = (const float*)d_in[1];
    float* out = (float*)d_out;
    double* partial = (double*)d_ws;  // NXT*NSEG*NB doubles = 12 KiB

    dim3 grid(NXT, NSEG, NB);
    ssim_main<<<grid, 64, 0, stream>>>(img1, img2, partial);
    ssim_final<<<1, 256, 0, stream>>>(partial, NXT * NSEG * NB, out);
}

// Round 2
// 132.111 us; speedup vs baseline: 1.2306x; 1.2306x over previous
//
#include <hip/hip_runtime.h>

#define CROPPX 4
#define H 504
#define W 504
#define IMG 512
#define NB 16
#define NCH 3
#define KS 11
#define RAD 5
#define TW 64               // output cols per block
#define STRIP (TW + 2*RAD)  // 74 input cols per block
#define RPS 28              // output rows per segment (18*28 = 504 exactly)
#define NSEG 18
#define NXT 8               // ceil(504/64): last tile has 56 valid cols
#define TOTAL (RPS + 2*RAD) // 38 row ingests per block

__global__ __launch_bounds__(64) void ssim_main(const float* __restrict__ img1,
                                                const float* __restrict__ img2,
                                                float* __restrict__ partial) {
    const int tid = threadIdx.x;
    const int gx0 = blockIdx.x * TW;   // first output col of tile
    const int y0  = blockIdx.y * RPS;  // first output row of segment
    const int b   = blockIdx.z;        // batch

    __shared__ float2 rowAB[STRIP];    // interleaved (img1, img2) row strip

    const float* p1 = img1 + (size_t)(b * NCH) * IMG * IMG + (size_t)CROPPX * IMG + CROPPX;
    const float* p2 = img2 + (size_t)(b * NCH) * IMG * IMG + (size_t)CROPPX * IMG + CROPPX;

    // register-resident history ring: 11 rows x 5 stats (indices compile-time)
    float r1[KS], r2[KS], r11[KS], r22[KS], r12[KS];
    #pragma unroll
    for (int j = 0; j < KS; ++j) { r1[j]=0.f; r2[j]=0.f; r11[j]=0.f; r22[j]=0.f; r12[j]=0.f; }

    float vs1 = 0.f, vs2 = 0.f, vs11 = 0.f, vs22 = 0.f, vs12 = 0.f;
    float ssum = 0.f;
    const float C1 = 6.5025f, C2 = 58.5225f;
    const float inv121 = 1.0f / 121.0f;
    const bool colValid = (gx0 + tid) < W;
    const int c0 = gx0 - RAD + tid;    // this lane's strip col (first 64)
    const int c1 = c0 + 64;            // second strip col (10 lanes)
    const bool lane2 = tid < (STRIP - 64);

    // prefetch row for iter = 0
    float a0 = 0.f, b0 = 0.f, a1 = 0.f, b1 = 0.f;
    {
        const int r = y0 - RAD;
        if ((unsigned)r < (unsigned)H) {
            const size_t ro = (size_t)r * IMG;
            if ((unsigned)c0 < (unsigned)W) { a0 = p1[ro + c0]; b0 = p2[ro + c0]; }
            if (lane2 && (unsigned)c1 < (unsigned)W) { a1 = p1[ro + c1]; b1 = p2[ro + c1]; }
        }
    }

    for (int base = 0; base < TOTAL; base += KS) {
        #pragma unroll
        for (int j = 0; j < KS; ++j) {
            const int iter = base + j;
            if (iter >= TOTAL) break;

            // publish staged row to LDS
            __syncthreads();
            rowAB[tid] = make_float2(a0, b0);
            if (lane2) rowAB[64 + tid] = make_float2(a1, b1);
            __syncthreads();

            // prefetch next row (overlaps with compute below)
            a0 = 0.f; b0 = 0.f; a1 = 0.f; b1 = 0.f;
            if (iter + 1 < TOTAL) {
                const int rn = y0 - RAD + iter + 1;
                if ((unsigned)rn < (unsigned)H) {
                    const size_t ro = (size_t)rn * IMG;
                    if ((unsigned)c0 < (unsigned)W) { a0 = p1[ro + c0]; b0 = p2[ro + c0]; }
                    if (lane2 && (unsigned)c1 < (unsigned)W) { a1 = p1[ro + c1]; b1 = p2[ro + c1]; }
                }
            }

            // horizontal 11-tap sums from LDS (output col = gx0 + tid)
            float h1 = 0.f, h2 = 0.f, h11 = 0.f, h22 = 0.f, h12 = 0.f;
            #pragma unroll
            for (int dx = 0; dx < KS; ++dx) {
                const float2 ab = rowAB[tid + dx];
                h1 += ab.x;
                h2 += ab.y;
                h11 = fmaf(ab.x, ab.x, h11);
                h22 = fmaf(ab.y, ab.y, h22);
                h12 = fmaf(ab.x, ab.y, h12);
            }

            // vertical sliding window; ring slot j == iter % 11 (base % 11 == 0)
            vs1  += h1  - r1[j];  r1[j]  = h1;
            vs2  += h2  - r2[j];  r2[j]  = h2;
            vs11 += h11 - r11[j]; r11[j] = h11;
            vs22 += h22 - r22[j]; r22[j] = h22;
            vs12 += h12 - r12[j]; r12[j] = h12;

            // window covers rows [iter-10, iter] => output row iter-5
            if (iter >= 2 * RAD && colValid) {
                const float mu1 = vs1 * inv121;
                const float mu2 = vs2 * inv121;
                const float mu1s = mu1 * mu1;
                const float mu2s = mu2 * mu2;
                const float m12  = mu1 * mu2;
                const float s1  = fmaf(vs11, inv121, -mu1s);
                const float s2  = fmaf(vs22, inv121, -mu2s);
                const float s12 = fmaf(vs12, inv121, -m12);
                const float num = (2.0f * m12 + C1) * (2.0f * s12 + C2);
                const float den = (mu1s + mu2s + C1) * (s1 + s2 + C2);
                ssum += num / den;
            }
        }
    }

    // wave (64-lane) reduction of ssum
    for (int off = 32; off > 0; off >>= 1)
        ssum += __shfl_down(ssum, off);
    if (tid == 0) {
        const int bidx = (blockIdx.z * gridDim.y + blockIdx.y) * gridDim.x + blockIdx.x;
        partial[bidx] = ssum;
    }
}

__global__ __launch_bounds__(256) void ssim_final(const float* __restrict__ partial,
                                                  int n, float* __restrict__ out) {
    __shared__ double sh[256];
    double s = 0.0;
    for (int i = threadIdx.x; i < n; i += 256) s += (double)partial[i];
    sh[threadIdx.x] = s;
    __syncthreads();
    for (int stride = 128; stride > 0; stride >>= 1) {
        if (threadIdx.x < stride) sh[threadIdx.x] += sh[threadIdx.x + stride];
        __syncthreads();
    }
    if (threadIdx.x == 0)
        out[0] = (float)(sh[0] / ((double)NB * (double)H * (double)W));
}

extern "C" void kernel_launch(void* const* d_in, const int* in_sizes, int n_in,
                              void* d_out, int out_size, void* d_ws, size_t ws_size,
                              hipStream_t stream) {
    const float* img1 = (const float*)d_in[0];
    const float* img2 = (const float*)d_in[1];
    float* out = (float*)d_out;
    float* partial = (float*)d_ws;  // NXT*NSEG*NB floats = 9.2 KiB

    dim3 grid(NXT, NSEG, NB);
    ssim_main<<<grid, 64, 0, stream>>>(img1, img2, partial);
    ssim_final<<<1, 256, 0, stream>>>(partial, NXT * NSEG * NB, out);
}